// Round 1
// baseline (98.786 us; speedup 1.0000x reference)
//
#include <hip/hip_runtime.h>

typedef __bf16 bf16;
typedef __bf16 bf16x4 __attribute__((ext_vector_type(4)));
typedef __bf16 bf16x8 __attribute__((ext_vector_type(8)));
typedef float f32x4 __attribute__((ext_vector_type(4)));

#define MFMA16(a, b, c) __builtin_amdgcn_mfma_f32_16x16x32_bf16(a, b, c, 0, 0, 0)

__device__ __forceinline__ void gload_lds16(const void* g, void* l) {
    __builtin_amdgcn_global_load_lds((const __attribute__((address_space(1))) void*)g,
                                     (__attribute__((address_space(3))) void*)l, 16, 0, 0);
}

__device__ __forceinline__ int clampi(int v, int lo, int hi) {
    return v < lo ? lo : (v > hi ? hi : v);
}

// ---------------- fp32 -> bf16 conversion (x, qkv_w, out_w) ----------------
// units of 4 floats: x 1048576, qkv_w 786432, out_w 262144  => 2097152 total
__global__ void convert3(const float* __restrict__ x, const float* __restrict__ wq,
                         const float* __restrict__ wo,
                         bf16* __restrict__ xb, bf16* __restrict__ wqb, bf16* __restrict__ wob) {
    int u = blockIdx.x * 256 + threadIdx.x;
    const float4* src;
    bf16* dst;
    int off;
    if (u < 1048576) { src = (const float4*)x;  dst = xb;  off = u; }
    else if (u < 1048576 + 786432) { src = (const float4*)wq; dst = wqb; off = u - 1048576; }
    else { src = (const float4*)wo; dst = wob; off = u - (1048576 + 786432); }
    float4 v = src[off];
    bf16x4 o = { (bf16)v.x, (bf16)v.y, (bf16)v.z, (bf16)v.w };
    *(bf16x4*)(dst + (size_t)off * 4) = o;
}

// ---------------- bf16 GEMM: C[m][n] = sum_k A[m][k]*B[n][k] + bias[n] ------
// BM=BN=128, BK=32, 256 thr (4 waves), each wave 64x64 via 4x4 of 16x16x32.
// EPI 0: scatter epilogue -> q[bh][t][64], k[bh][t][64], vT[bh][64][t] (bf16)
// EPI 1: fp32 epilogue -> outf[m][NN]
template <int NN, int EPI>
__global__ __launch_bounds__(256, 2) void gemm_bt(
    const bf16* __restrict__ A, const bf16* __restrict__ B, const float* __restrict__ bias,
    bf16* __restrict__ qb, bf16* __restrict__ kb, bf16* __restrict__ vtb,
    float* __restrict__ outf) {
    constexpr int K = 1024;
    constexpr int KT = K / 32;
    __shared__ bf16 As[2][128 * 32];
    __shared__ bf16 Bs[2][128 * 32];
    const int tid = threadIdx.x;
    const int w = tid >> 6, lane = tid & 63;
    const int c = lane & 15, g = lane >> 4;
    const int wr = w >> 1, wc = w & 1;
    const int bn = blockIdx.x, bm = blockIdx.y;
    const size_t abase = (size_t)bm * 128 * K;
    const size_t bbase = (size_t)bn * 128 * K;

    f32x4 acc[4][4] = {};

    auto stage = [&](int buf, int k0) {
#pragma unroll
        for (int i = 0; i < 2; ++i) {
            int u = i * 256 + tid;
            const bf16* ga = A + abase + (size_t)(u >> 2) * K + k0 + (u & 3) * 8;
            gload_lds16(ga, &As[buf][(i * 256 + w * 64) * 8]);
            const bf16* gb = B + bbase + (size_t)(u >> 2) * K + k0 + (u & 3) * 8;
            gload_lds16(gb, &Bs[buf][(i * 256 + w * 64) * 8]);
        }
    };

    stage(0, 0);
    __syncthreads();
    int cur = 0;
    for (int kt = 0; kt < KT; ++kt) {
        if (kt + 1 < KT) stage(cur ^ 1, (kt + 1) * 32);
        bf16x8 af[4], bfr[4];
#pragma unroll
        for (int mi = 0; mi < 4; ++mi)
            af[mi] = *(const bf16x8*)&As[cur][(wr * 64 + mi * 16 + c) * 32 + g * 8];
#pragma unroll
        for (int ni = 0; ni < 4; ++ni)
            bfr[ni] = *(const bf16x8*)&Bs[cur][(wc * 64 + ni * 16 + c) * 32 + g * 8];
#pragma unroll
        for (int mi = 0; mi < 4; ++mi)
#pragma unroll
            for (int ni = 0; ni < 4; ++ni)
                acc[mi][ni] = MFMA16(af[mi], bfr[ni], acc[mi][ni]);
        __syncthreads();
        cur ^= 1;
    }

#pragma unroll
    for (int mi = 0; mi < 4; ++mi) {
        int m0 = bm * 128 + wr * 64 + mi * 16 + g * 4;
#pragma unroll
        for (int ni = 0; ni < 4; ++ni) {
            int n = bn * 128 + wc * 64 + ni * 16 + c;
            float bv = bias[n];
            f32x4 v = acc[mi][ni];
            if constexpr (EPI == 0) {
                int which = n >> 10;
                int h = (n >> 6) & 15;
                int d = n & 63;
                int b = m0 >> 11;
                int t0 = m0 & 2047;
                int bh = b * 16 + h;
                if (which == 2) {
                    bf16x4 pv = { (bf16)(v[0] + bv), (bf16)(v[1] + bv),
                                  (bf16)(v[2] + bv), (bf16)(v[3] + bv) };
                    *(bf16x4*)&vtb[((size_t)bh * 64 + d) * 2048 + t0] = pv;
                } else {
                    bf16* dst = (which == 0 ? qb : kb) + (size_t)bh * 2048 * 64;
#pragma unroll
                    for (int r = 0; r < 4; ++r)
                        dst[(size_t)(t0 + r) * 64 + d] = (bf16)(v[r] + bv);
                }
            } else {
#pragma unroll
                for (int r = 0; r < 4; ++r)
                    outf[(size_t)(m0 + r) * NN + n] = v[r] + bv;
            }
        }
    }
}

// ---------------- windowed decay attention ---------------------------------
// One block = (bh, 64-query tile). 256-key window [q0-96, q0+160).
// Exact softmax (two-pass max via LDS). Wave w: 64-key slice for S^T,
// then 16-query slice for PV.
__global__ __launch_bounds__(256, 2) void attn_win(
    const bf16* __restrict__ qb, const bf16* __restrict__ kb,
    const bf16* __restrict__ vtb, const float* __restrict__ decay,
    bf16* __restrict__ ao) {
    const int tid = threadIdx.x;
    const int w = tid >> 6, lane = tid & 63;
    const int c = lane & 15, g = lane >> 4;
    const int blk = blockIdx.x;
    const int qt = blk & 31, bh = blk >> 5;
    const int h = bh & 15, b = bh >> 4;
    const int q0 = qt * 64;
    const int ks = q0 - 96;
    const bf16* Q = qb + (size_t)bh * 2048 * 64;
    const bf16* Kp = kb + (size_t)bh * 2048 * 64;
    const bf16* VT = vtb + (size_t)bh * 64 * 2048;
    const float alpha = log1pf(__expf(decay[h]));

    __shared__ bf16 P[64 * 264];   // [q][k], stride 264 (528B rows, 16B-aligned)
    __shared__ float mld[4][64];
    __shared__ float lld[4][64];

    // ---- S^T = K . Q^T for this wave's 64 keys x all 64 queries ----
    bf16x8 qf[4][2], kf[4][2];
#pragma unroll
    for (int i = 0; i < 4; ++i) {
        int tq = q0 + i * 16 + c;
        int tk = clampi(ks + w * 64 + i * 16 + c, 0, 2047);
#pragma unroll
        for (int dh = 0; dh < 2; ++dh) {
            qf[i][dh] = *(const bf16x8*)(Q + (size_t)tq * 64 + dh * 32 + g * 8);
            kf[i][dh] = *(const bf16x8*)(Kp + (size_t)tk * 64 + dh * 32 + g * 8);
        }
    }
    f32x4 s[4][4] = {};  // [key-frag][q-frag]
#pragma unroll
    for (int dh = 0; dh < 2; ++dh)
#pragma unroll
        for (int ki = 0; ki < 4; ++ki)
#pragma unroll
            for (int qi = 0; qi < 4; ++qi)
                s[ki][qi] = MFMA16(kf[ki][dh], qf[qi][dh], s[ki][qi]);

    // ---- scale + decay bias + mask; wave-local row max ----
    float mx[4] = { -1e30f, -1e30f, -1e30f, -1e30f };
#pragma unroll
    for (int ki = 0; ki < 4; ++ki)
#pragma unroll
        for (int qi = 0; qi < 4; ++qi) {
            int tq = q0 + qi * 16 + c;
#pragma unroll
            for (int r = 0; r < 4; ++r) {
                int tk = ks + w * 64 + ki * 16 + g * 4 + r;
                float val = (tk < 0 || tk >= 2048)
                                ? -1e30f
                                : s[ki][qi][r] * 0.125f - alpha * fabsf((float)(tq - tk));
                s[ki][qi][r] = val;
                mx[qi] = fmaxf(mx[qi], val);
            }
        }
#pragma unroll
    for (int qi = 0; qi < 4; ++qi) {
        mx[qi] = fmaxf(mx[qi], __shfl_xor(mx[qi], 16));
        mx[qi] = fmaxf(mx[qi], __shfl_xor(mx[qi], 32));
    }
    if (lane < 16) {
#pragma unroll
        for (int qi = 0; qi < 4; ++qi) mld[w][qi * 16 + lane] = mx[qi];
    }
    __syncthreads();

    // ---- global max, exp, row-sum, P -> LDS (bf16) ----
    float mg[4], ls[4] = {};
#pragma unroll
    for (int qi = 0; qi < 4; ++qi)
        mg[qi] = fmaxf(fmaxf(mld[0][qi * 16 + c], mld[1][qi * 16 + c]),
                       fmaxf(mld[2][qi * 16 + c], mld[3][qi * 16 + c]));
#pragma unroll
    for (int ki = 0; ki < 4; ++ki)
#pragma unroll
        for (int qi = 0; qi < 4; ++qi)
#pragma unroll
            for (int r = 0; r < 4; ++r) {
                float p = __expf(s[ki][qi][r] - mg[qi]);
                s[ki][qi][r] = p;
                ls[qi] += p;
            }
#pragma unroll
    for (int qi = 0; qi < 4; ++qi) {
        ls[qi] += __shfl_xor(ls[qi], 16);
        ls[qi] += __shfl_xor(ls[qi], 32);
    }
    if (lane < 16) {
#pragma unroll
        for (int qi = 0; qi < 4; ++qi) lld[w][qi * 16 + lane] = ls[qi];
    }
#pragma unroll
    for (int ki = 0; ki < 4; ++ki)
#pragma unroll
        for (int qi = 0; qi < 4; ++qi) {
            bf16x4 pv = { (bf16)s[ki][qi][0], (bf16)s[ki][qi][1],
                          (bf16)s[ki][qi][2], (bf16)s[ki][qi][3] };
            *(bf16x4*)&P[(qi * 16 + c) * 264 + w * 64 + ki * 16 + g * 4] = pv;
        }
    __syncthreads();

    // ---- O = P . V for this wave's 16 query rows ----
    f32x4 o[4] = {};
#pragma unroll
    for (int kst = 0; kst < 8; ++kst) {
        bf16x8 pa = *(const bf16x8*)&P[(w * 16 + c) * 264 + kst * 32 + g * 8];
        int tb = clampi(ks + kst * 32 + g * 8, 0, 2040);  // 8-aligned validity => safe
#pragma unroll
        for (int nf = 0; nf < 4; ++nf) {
            bf16x8 vb = *(const bf16x8*)(VT + (size_t)(nf * 16 + c) * 2048 + tb);
            o[nf] = MFMA16(pa, vb, o[nf]);
        }
    }
    float lsum[4];
#pragma unroll
    for (int r = 0; r < 4; ++r) {
        int qr = w * 16 + g * 4 + r;
        lsum[r] = lld[0][qr] + lld[1][qr] + lld[2][qr] + lld[3][qr];
    }
#pragma unroll
    for (int nf = 0; nf < 4; ++nf) {
        int dd = h * 64 + nf * 16 + c;
#pragma unroll
        for (int r = 0; r < 4; ++r) {
            int tq = q0 + w * 16 + g * 4 + r;
            ao[(size_t)(b * 2048 + tq) * 1024 + dd] = (bf16)(o[nf][r] / lsum[r]);
        }
    }
}

// ---------------- launch ----------------------------------------------------
extern "C" void kernel_launch(void* const* d_in, const int* in_sizes, int n_in,
                              void* d_out, int out_size, void* d_ws, size_t ws_size,
                              hipStream_t stream) {
    const float* x = (const float*)d_in[0];
    const float* qkv_w = (const float*)d_in[1];
    const float* qkv_b = (const float*)d_in[2];
    const float* out_w = (const float*)d_in[3];
    const float* out_b = (const float*)d_in[4];
    const float* decay = (const float*)d_in[5];
    float* out = (float*)d_out;

    char* ws = (char*)d_ws;
    bf16* xb   = (bf16*)(ws);                       // 8 MB
    bf16* wqb  = (bf16*)(ws + 8388608);             // 6 MB
    bf16* wob  = (bf16*)(ws + 14680064);            // 2 MB
    bf16* qbuf = (bf16*)(ws + 16777216);            // 8 MB  [bh][t][64]
    bf16* kbuf = (bf16*)(ws + 25165824);            // 8 MB  [bh][t][64]
    bf16* vtb  = (bf16*)(ws + 33554432);            // 8 MB  [bh][64][t]
    bf16* aob  = (bf16*)(ws + 41943040);            // 8 MB  [4096][1024]

    convert3<<<dim3(8192), dim3(256), 0, stream>>>(x, qkv_w, out_w, xb, wqb, wob);
    gemm_bt<3072, 0><<<dim3(24, 32), dim3(256), 0, stream>>>(
        xb, wqb, qkv_b, qbuf, kbuf, vtb, (float*)nullptr);
    attn_win<<<dim3(1024), dim3(256), 0, stream>>>(qbuf, kbuf, vtb, decay, aob);
    gemm_bt<1024, 1><<<dim3(8, 32), dim3(256), 0, stream>>>(
        aob, wob, out_b, (bf16*)nullptr, (bf16*)nullptr, (bf16*)nullptr, out);
}

// Round 2
// 81.785 us; speedup vs baseline: 1.2079x; 1.2079x over previous
//
#include <hip/hip_runtime.h>

typedef __bf16 bf16;
typedef __bf16 bf16x4 __attribute__((ext_vector_type(4)));
typedef __bf16 bf16x8 __attribute__((ext_vector_type(8)));
typedef float f32x4 __attribute__((ext_vector_type(4)));

#define MFMA16(a, b, c) __builtin_amdgcn_mfma_f32_16x16x32_bf16(a, b, c, 0, 0, 0)

__device__ __forceinline__ void gload_lds16(const void* g, void* l) {
    __builtin_amdgcn_global_load_lds((const __attribute__((address_space(1))) void*)g,
                                     (__attribute__((address_space(3))) void*)l, 16, 0, 0);
}

__device__ __forceinline__ int clampi(int v, int lo, int hi) {
    return v < lo ? lo : (v > hi ? hi : v);
}

// ---------------- fp32 -> bf16 conversion (x, qkv_w, out_w) ----------------
__global__ void convert3(const float* __restrict__ x, const float* __restrict__ wq,
                         const float* __restrict__ wo,
                         bf16* __restrict__ xb, bf16* __restrict__ wqb, bf16* __restrict__ wob) {
    int u = blockIdx.x * 256 + threadIdx.x;
    const float4* src;
    bf16* dst;
    int off;
    if (u < 1048576) { src = (const float4*)x;  dst = xb;  off = u; }
    else if (u < 1048576 + 786432) { src = (const float4*)wq; dst = wqb; off = u - 1048576; }
    else { src = (const float4*)wo; dst = wob; off = u - (1048576 + 786432); }
    float4 v = src[off];
    bf16x4 o = { (bf16)v.x, (bf16)v.y, (bf16)v.z, (bf16)v.w };
    *(bf16x4*)(dst + (size_t)off * 4) = o;
}

// ---------------- bf16 GEMM: C[m][n] = sum_k A[m][k]*B[n][k] + bias[n] ------
template <int NN, int EPI>
__global__ __launch_bounds__(256, 2) void gemm_bt(
    const bf16* __restrict__ A, const bf16* __restrict__ B, const float* __restrict__ bias,
    bf16* __restrict__ qb, bf16* __restrict__ kb, bf16* __restrict__ vtb,
    float* __restrict__ outf) {
    constexpr int K = 1024;
    constexpr int KT = K / 32;
    __shared__ bf16 As[2][128 * 32];
    __shared__ bf16 Bs[2][128 * 32];
    const int tid = threadIdx.x;
    const int w = tid >> 6, lane = tid & 63;
    const int c = lane & 15, g = lane >> 4;
    const int wr = w >> 1, wc = w & 1;
    const int bn = blockIdx.x, bm = blockIdx.y;
    const size_t abase = (size_t)bm * 128 * K;
    const size_t bbase = (size_t)bn * 128 * K;

    f32x4 acc[4][4] = {};

    auto stage = [&](int buf, int k0) {
#pragma unroll
        for (int i = 0; i < 2; ++i) {
            int u = i * 256 + tid;
            const bf16* ga = A + abase + (size_t)(u >> 2) * K + k0 + (u & 3) * 8;
            gload_lds16(ga, &As[buf][(i * 256 + w * 64) * 8]);
            const bf16* gb = B + bbase + (size_t)(u >> 2) * K + k0 + (u & 3) * 8;
            gload_lds16(gb, &Bs[buf][(i * 256 + w * 64) * 8]);
        }
    };

    stage(0, 0);
    __syncthreads();
    int cur = 0;
    for (int kt = 0; kt < KT; ++kt) {
        if (kt + 1 < KT) stage(cur ^ 1, (kt + 1) * 32);
        bf16x8 af[4], bfr[4];
#pragma unroll
        for (int mi = 0; mi < 4; ++mi)
            af[mi] = *(const bf16x8*)&As[cur][(wr * 64 + mi * 16 + c) * 32 + g * 8];
#pragma unroll
        for (int ni = 0; ni < 4; ++ni)
            bfr[ni] = *(const bf16x8*)&Bs[cur][(wc * 64 + ni * 16 + c) * 32 + g * 8];
#pragma unroll
        for (int mi = 0; mi < 4; ++mi)
#pragma unroll
            for (int ni = 0; ni < 4; ++ni)
                acc[mi][ni] = MFMA16(af[mi], bfr[ni], acc[mi][ni]);
        __syncthreads();
        cur ^= 1;
    }

#pragma unroll
    for (int mi = 0; mi < 4; ++mi) {
        int m0 = bm * 128 + wr * 64 + mi * 16 + g * 4;
#pragma unroll
        for (int ni = 0; ni < 4; ++ni) {
            int n = bn * 128 + wc * 64 + ni * 16 + c;
            float bv = bias[n];
            f32x4 v = acc[mi][ni];
            if constexpr (EPI == 0) {
                int which = n >> 10;
                int h = (n >> 6) & 15;
                int d = n & 63;
                int b = m0 >> 11;
                int t0 = m0 & 2047;
                int bh = b * 16 + h;
                if (which == 2) {
                    bf16x4 pv = { (bf16)(v[0] + bv), (bf16)(v[1] + bv),
                                  (bf16)(v[2] + bv), (bf16)(v[3] + bv) };
                    *(bf16x4*)&vtb[((size_t)bh * 64 + d) * 2048 + t0] = pv;
                } else {
                    bf16* dst = (which == 0 ? qb : kb) + (size_t)bh * 2048 * 64;
#pragma unroll
                    for (int r = 0; r < 4; ++r)
                        dst[(size_t)(t0 + r) * 64 + d] = (bf16)(v[r] + bv);
                }
            } else {
#pragma unroll
                for (int r = 0; r < 4; ++r)
                    outf[(size_t)(m0 + r) * NN + n] = v[r] + bv;
            }
        }
    }
}

// ---------------- windowed decay attention, v2 -----------------------------
// Block = (bh, 64-query tile). Window 128 keys [q0-32, q0+96).
// 4 waves; wave w owns queries q0+w*16 .. +15 for QK^T cols, PV rows, O rows.
// K (16KB) and VT (16KB) async-staged to LDS with XOR swizzle; P reuses K
// region after barrier 2; O bounced through P region for coalesced stores.
__global__ __launch_bounds__(256, 4) void attn_win(
    const bf16* __restrict__ qb, const bf16* __restrict__ kb,
    const bf16* __restrict__ vtb, const float* __restrict__ decay,
    bf16* __restrict__ ao) {
    __shared__ __attribute__((aligned(16))) char kp_buf[16384];  // K / P / O-bounce
    __shared__ __attribute__((aligned(16))) char vt_buf[16384];  // VT
    const int tid = threadIdx.x;
    const int w = tid >> 6, lane = tid & 63;
    const int c = lane & 15, g = lane >> 4;
    // XCD-chunked swizzle: 128 consecutive logical tiles per XCD
    const int phys = blockIdx.x;
    const int blk = (phys & 7) * 128 + (phys >> 3);
    const int qt = blk & 31, bh = blk >> 5;
    const int h = bh & 15, b = bh >> 4;
    const int q0 = qt * 64;
    const int ks = q0 - 32;
    const bf16* Q = qb + (size_t)bh * 2048 * 64;
    const char* Kg = (const char*)(kb + (size_t)bh * 2048 * 64);
    const char* Vg = (const char*)(vtb + (size_t)bh * 64 * 2048);
    const float alpha = log1pf(__expf(decay[h]));

    // ---- async stage K: 128 rows x 128B, swizzle byte ^= ((row&7)<<4) ----
#pragma unroll
    for (int i = 0; i < 4; ++i) {
        int u = i * 256 + tid;
        int r = u >> 3;
        int bb = ((u & 7) * 16) ^ ((r & 7) << 4);
        int t = clampi(ks + r, 0, 2047);
        gload_lds16(Kg + (size_t)t * 128 + bb, kp_buf + u * 16);
    }
    // ---- async stage VT: 64 rows x 256B (128 keys), same swizzle ----
#pragma unroll
    for (int i = 0; i < 4; ++i) {
        int u = i * 256 + tid;
        int d = u >> 4;
        int bb = ((u & 15) * 16) ^ ((d & 7) << 4);
        int kbyte = clampi(ks * 2 + bb, 0, 4080);
        gload_lds16(Vg + (size_t)d * 4096 + kbyte, vt_buf + u * 16);
    }

    // Q fragments direct from global (latency hidden under staging drain)
    bf16x8 qf[2];
#pragma unroll
    for (int dh = 0; dh < 2; ++dh)
        qf[dh] = *(const bf16x8*)(Q + (size_t)(q0 + w * 16 + c) * 64 + dh * 32 + g * 8);

    __syncthreads();  // staging drained (compiler emits vmcnt(0) before barrier)

    // ---- QK^T: S^T[128 keys][16 queries], swapped operands ----
    f32x4 s[8] = {};
#pragma unroll
    for (int dh = 0; dh < 2; ++dh)
#pragma unroll
        for (int ki = 0; ki < 8; ++ki) {
            int r = ki * 16 + c;
            bf16x8 kf = *(const bf16x8*)(kp_buf + r * 128 +
                                         ((dh * 64 + g * 16) ^ ((r & 7) << 4)));
            s[ki] = MFMA16(kf, qf[dh], s[ki]);
        }

    // ---- scale + decay + mask + in-wave softmax (col c = query) ----
    const int tq = q0 + w * 16 + c;
    float mx = -1e30f;
#pragma unroll
    for (int ki = 0; ki < 8; ++ki)
#pragma unroll
        for (int r = 0; r < 4; ++r) {
            int tk = ks + ki * 16 + g * 4 + r;
            float val = (tk < 0 || tk > 2047)
                            ? -1e30f
                            : s[ki][r] * 0.125f - alpha * fabsf((float)(tq - tk));
            s[ki][r] = val;
            mx = fmaxf(mx, val);
        }
    mx = fmaxf(mx, __shfl_xor(mx, 16));
    mx = fmaxf(mx, __shfl_xor(mx, 32));
    float ls = 0.f;
#pragma unroll
    for (int ki = 0; ki < 8; ++ki)
#pragma unroll
        for (int r = 0; r < 4; ++r) {
            float p = __expf(s[ki][r] - mx);
            s[ki][r] = p;
            ls += p;
        }
    ls += __shfl_xor(ls, 16);
    ls += __shfl_xor(ls, 32);

    __syncthreads();  // all waves done reading K; safe to overwrite with P

    // ---- P -> LDS (bf16, rows 256B, swizzled); own rows only ----
#pragma unroll
    for (int ki = 0; ki < 8; ++ki) {
        bf16x4 pv = { (bf16)s[ki][0], (bf16)s[ki][1], (bf16)s[ki][2], (bf16)s[ki][3] };
        *(bf16x4*)(kp_buf + (w * 16 + c) * 256 + ((ki * 32 + g * 8) ^ ((c & 7) << 4))) = pv;
    }
    asm volatile("s_waitcnt lgkmcnt(0)" ::: "memory");
    __builtin_amdgcn_sched_barrier(0);

    // ---- PV: O[16 q][64 d] per wave, all from LDS ----
    f32x4 o[4] = {};
#pragma unroll
    for (int kst = 0; kst < 4; ++kst) {
        bf16x8 pa = *(const bf16x8*)(kp_buf + (w * 16 + c) * 256 +
                                     ((kst * 64 + g * 16) ^ ((c & 7) << 4)));
#pragma unroll
        for (int nf = 0; nf < 4; ++nf) {
            int d = nf * 16 + c;
            bf16x8 vb = *(const bf16x8*)(vt_buf + d * 256 +
                                         ((kst * 64 + g * 16) ^ ((d & 7) << 4)));
            o[nf] = MFMA16(pa, vb, o[nf]);
        }
    }

    // row sums for this lane's output rows (q_local = g*4+r lives at lane q_local)
    float lsum[4];
#pragma unroll
    for (int r = 0; r < 4; ++r) lsum[r] = __shfl(ls, g * 4 + r);

    // ---- O bounce through own P region (rows 128B, swizzled) ----
    char* Ob = kp_buf + w * 4096;
#pragma unroll
    for (int nf = 0; nf < 4; ++nf)
#pragma unroll
        for (int r = 0; r < 4; ++r) {
            int q = g * 4 + r;
            int d = nf * 16 + c;
            *(bf16*)(Ob + q * 128 + ((d * 2) ^ ((q & 7) << 4))) =
                (bf16)(o[nf][r] / lsum[r]);
        }
    asm volatile("s_waitcnt lgkmcnt(0)" ::: "memory");
    __builtin_amdgcn_sched_barrier(0);

    // ---- coalesced store: 4 lanes per query row, 2x bf16x8 each ----
    {
        int q = lane >> 2;
        int ch = lane & 3;
        int t = q0 + w * 16 + q;
        bf16* dst = ao + (size_t)(b * 2048 + t) * 1024 + h * 64 + ch * 16;
#pragma unroll
        for (int j = 0; j < 2; ++j) {
            bf16x8 v = *(const bf16x8*)(Ob + q * 128 + ((ch * 32 + j * 16) ^ ((q & 7) << 4)));
            *(bf16x8*)(dst + j * 8) = v;
        }
    }
}

// ---------------- launch ----------------------------------------------------
extern "C" void kernel_launch(void* const* d_in, const int* in_sizes, int n_in,
                              void* d_out, int out_size, void* d_ws, size_t ws_size,
                              hipStream_t stream) {
    const float* x = (const float*)d_in[0];
    const float* qkv_w = (const float*)d_in[1];
    const float* qkv_b = (const float*)d_in[2];
    const float* out_w = (const float*)d_in[3];
    const float* out_b = (const float*)d_in[4];
    const float* decay = (const float*)d_in[5];
    float* out = (float*)d_out;

    char* ws = (char*)d_ws;
    bf16* xb   = (bf16*)(ws);                       // 8 MB
    bf16* wqb  = (bf16*)(ws + 8388608);             // 6 MB
    bf16* wob  = (bf16*)(ws + 14680064);            // 2 MB
    bf16* qbuf = (bf16*)(ws + 16777216);            // 8 MB  [bh][t][64]
    bf16* kbuf = (bf16*)(ws + 25165824);            // 8 MB  [bh][t][64]
    bf16* vtb  = (bf16*)(ws + 33554432);            // 8 MB  [bh][64][t]
    bf16* aob  = (bf16*)(ws + 41943040);            // 8 MB  [4096][1024]

    convert3<<<dim3(8192), dim3(256), 0, stream>>>(x, qkv_w, out_w, xb, wqb, wob);
    gemm_bt<3072, 0><<<dim3(24, 32), dim3(256), 0, stream>>>(
        xb, wqb, qkv_b, qbuf, kbuf, vtb, (float*)nullptr);
    attn_win<<<dim3(1024), dim3(256), 0, stream>>>(qbuf, kbuf, vtb, decay, aob);
    gemm_bt<1024, 1><<<dim3(8, 32), dim3(256), 0, stream>>>(
        aob, wob, out_b, (bf16*)nullptr, (bf16*)nullptr, (bf16*)nullptr, out);
}